// Round 6
// baseline (572.371 us; speedup 1.0000x reference)
//
#include <hip/hip_runtime.h>
#include <math.h>

#define NPG 1000
#define KTOP 500
#define C 64
#define EPG 16000   // edges per graph = NPG * DEG

// ---------------- fused per-graph CSR build: count + scan + scatter in LDS ----------------
__global__ __launch_bounds__(256) void build_graph_k(const int* __restrict__ ei, int E,
                                                     int* __restrict__ deg,
                                                     float* __restrict__ dinv,
                                                     int* __restrict__ off,
                                                     int* __restrict__ csr) {
    int g = blockIdx.x, t = threadIdx.x;
    __shared__ int cnt[NPG];               // counts, then cursors
    __shared__ int soff[NPG];              // local start offsets
    __shared__ unsigned short lcsr[EPG];   // src local ids, dst-grouped
    __shared__ int red[256];
    const int gbase = g * NPG;
    const int ebase = g * EPG;
    const int* __restrict__ srcp = ei + ebase;
    const int* __restrict__ dstp = ei + E + ebase;

    for (int i = t; i < NPG; i += 256) cnt[i] = 0;
    __syncthreads();
    for (int i = t; i < EPG; i += 256) atomicAdd(&cnt[dstp[i] - gbase], 1);
    __syncthreads();
    int base = t * 4;
    int v0 = 0, v1 = 0, v2 = 0, v3 = 0;
    if (base + 0 < NPG) v0 = cnt[base + 0];
    if (base + 1 < NPG) v1 = cnt[base + 1];
    if (base + 2 < NPG) v2 = cnt[base + 2];
    if (base + 3 < NPG) v3 = cnt[base + 3];
    int s = v0 + v1 + v2 + v3;
    red[t] = s;
    __syncthreads();
    for (int o = 1; o < 256; o <<= 1) {
        int xx = (t >= o) ? red[t - o] : 0;
        __syncthreads();
        red[t] += xx;
        __syncthreads();
    }
    int p = red[t] - s;
    if (base + 0 < NPG) { soff[base + 0] = p; p += v0; }
    if (base + 1 < NPG) { soff[base + 1] = p; p += v1; }
    if (base + 2 < NPG) { soff[base + 2] = p; p += v2; }
    if (base + 3 < NPG) { soff[base + 3] = p; p += v3; }
    __syncthreads();
    for (int i = t; i < NPG; i += 256) {
        int d = cnt[i];
        deg[gbase + i] = d;
        dinv[gbase + i] = 1.0f / sqrtf((float)(d + 1));
        off[gbase + i] = ebase + soff[i];
    }
    __syncthreads();
    for (int i = t; i < NPG; i += 256) cnt[i] = soff[i];
    __syncthreads();
    for (int i = t; i < EPG; i += 256) {
        int d = dstp[i] - gbase;
        int pos = atomicAdd(&cnt[d], 1);
        lcsr[pos] = (unsigned short)(srcp[i] - gbase);
    }
    __syncthreads();
    int4* co = (int4*)(csr + ebase);
    for (int i = t; i < EPG / 4; i += 256) {
        int4 v;
        v.x = gbase + (int)lcsr[i * 4 + 0];
        v.y = gbase + (int)lcsr[i * 4 + 1];
        v.z = gbase + (int)lcsr[i * 4 + 2];
        v.w = gbase + (int)lcsr[i * 4 + 3];
        co[i] = v;
    }
}

// ---------------- h = x @ W : register-tiled, 2 rows/thread, W in LDS ----------------
__global__ __launch_bounds__(256) void gemm_k(const float* __restrict__ x,
                                              const float* __restrict__ W,
                                              float* __restrict__ h, int N) {
    __shared__ float sW[C * C];
    int t = threadIdx.x;
    for (int i = t; i < C * C / 4; i += 256) ((float4*)sW)[i] = ((const float4*)W)[i];
    __syncthreads();
    int r0 = blockIdx.x * 512 + t;
    int r1 = r0 + 256;
    if (r0 >= N) return;
    bool has1 = (r1 < N);
    const float4* x0 = (const float4*)(x + (size_t)r0 * C);
    const float4* x1 = (const float4*)(x + (size_t)(has1 ? r1 : r0) * C);
    float acc0[C], acc1[C];
#pragma unroll
    for (int i = 0; i < C; ++i) { acc0[i] = 0.f; acc1[i] = 0.f; }
    float4 a0 = x0[0], a1 = x1[0];
    for (int k4 = 0; k4 < 16; ++k4) {
        float4 b0, b1;
        if (k4 < 15) { b0 = x0[k4 + 1]; b1 = x1[k4 + 1]; }
        const float4* wr = (const float4*)(sW + k4 * 4 * C);
        const float* a0f = (const float*)&a0;
        const float* a1f = (const float*)&a1;
#pragma unroll
        for (int c4 = 0; c4 < 16; ++c4) {
            float4 w[4];
            w[0] = wr[c4]; w[1] = wr[16 + c4]; w[2] = wr[32 + c4]; w[3] = wr[48 + c4];
            const float* wf = (const float*)w;
#pragma unroll
            for (int j = 0; j < 4; ++j) {
                float s0 = acc0[c4 * 4 + j], s1 = acc1[c4 * 4 + j];
#pragma unroll
                for (int kk = 0; kk < 4; ++kk) {
                    float wv = wf[kk * 4 + j];
                    s0 = fmaf(a0f[kk], wv, s0);
                    s1 = fmaf(a1f[kk], wv, s1);
                }
                acc0[c4 * 4 + j] = s0; acc1[c4 * 4 + j] = s1;
            }
        }
        a0 = b0; a1 = b1;
    }
    float4* h0 = (float4*)(h + (size_t)r0 * C);
#pragma unroll
    for (int q = 0; q < 16; ++q) h0[q] = ((float4*)acc0)[q];
    if (has1) {
        float4* h1 = (float4*)(h + (size_t)r1 * C);
#pragma unroll
        for (int q = 0; q < 16; ++q) h1[q] = ((float4*)acc1)[q];
    }
}

// ---------------- gather aggregation + fused centroid partial ----------------
// XCD-swizzled (graph stays in one XCD's L2); unroll-8 dual accumulators for MLP;
// per-block channel sums atomically added into cenacc[g*C+c].
__global__ __launch_bounds__(256) void gather_k(const int* __restrict__ csr,
                                                const int* __restrict__ off,
                                                const int* __restrict__ deg,
                                                const float* __restrict__ h,
                                                const float* __restrict__ dinv,
                                                const float* __restrict__ bias,
                                                float* __restrict__ out2,
                                                float* __restrict__ cenacc, int N, int B) {
    int b = blockIdx.x;
    int wave = threadIdx.x >> 6;
    int lane = threadIdx.x & 63;
    int node_base;
    if ((B & 7) == 0) {
        int xcd = b & 7, slot = b >> 3;
        int gpx = B >> 3;
        int g = xcd * gpx + slot / (NPG / 4);
        int blkin = slot % (NPG / 4);
        node_base = g * NPG + blkin * 4;
    } else {
        node_base = b * 4;
    }
    int node = node_base + wave;
    __shared__ float red[256];
    float val = 0.f;
    if (node < N) {
        int o0 = off[node], dg = deg[node];
        int sv = 0; float wv = 0.f;
        if (lane < dg) { sv = csr[o0 + lane]; wv = dinv[sv]; }
        float acc0 = 0.f, acc1 = 0.f;
        int jmax = dg < 64 ? dg : 64;
        int j = 0;
        for (; j + 8 <= jmax; j += 8) {
            int   s0 = __shfl(sv, j + 0); float w0 = __shfl(wv, j + 0);
            int   s1 = __shfl(sv, j + 1); float w1 = __shfl(wv, j + 1);
            int   s2 = __shfl(sv, j + 2); float w2 = __shfl(wv, j + 2);
            int   s3 = __shfl(sv, j + 3); float w3 = __shfl(wv, j + 3);
            int   s4 = __shfl(sv, j + 4); float w4 = __shfl(wv, j + 4);
            int   s5 = __shfl(sv, j + 5); float w5 = __shfl(wv, j + 5);
            int   s6 = __shfl(sv, j + 6); float w6 = __shfl(wv, j + 6);
            int   s7 = __shfl(sv, j + 7); float w7 = __shfl(wv, j + 7);
            float h0 = h[(size_t)s0 * C + lane];
            float h1 = h[(size_t)s1 * C + lane];
            float h2 = h[(size_t)s2 * C + lane];
            float h3 = h[(size_t)s3 * C + lane];
            float h4 = h[(size_t)s4 * C + lane];
            float h5 = h[(size_t)s5 * C + lane];
            float h6 = h[(size_t)s6 * C + lane];
            float h7 = h[(size_t)s7 * C + lane];
            acc0 = fmaf(h0, w0, acc0);
            acc1 = fmaf(h1, w1, acc1);
            acc0 = fmaf(h2, w2, acc0);
            acc1 = fmaf(h3, w3, acc1);
            acc0 = fmaf(h4, w4, acc0);
            acc1 = fmaf(h5, w5, acc1);
            acc0 = fmaf(h6, w6, acc0);
            acc1 = fmaf(h7, w7, acc1);
        }
        for (; j + 4 <= jmax; j += 4) {
            int   s0 = __shfl(sv, j + 0); float w0 = __shfl(wv, j + 0);
            int   s1 = __shfl(sv, j + 1); float w1 = __shfl(wv, j + 1);
            int   s2 = __shfl(sv, j + 2); float w2 = __shfl(wv, j + 2);
            int   s3 = __shfl(sv, j + 3); float w3 = __shfl(wv, j + 3);
            float h0 = h[(size_t)s0 * C + lane];
            float h1 = h[(size_t)s1 * C + lane];
            float h2 = h[(size_t)s2 * C + lane];
            float h3 = h[(size_t)s3 * C + lane];
            acc0 = fmaf(h0, w0, acc0);
            acc1 = fmaf(h1, w1, acc1);
            acc0 = fmaf(h2, w2, acc0);
            acc1 = fmaf(h3, w3, acc1);
        }
        for (; j < jmax; ++j) {
            int s = __shfl(sv, j); float w = __shfl(wv, j);
            acc0 = fmaf(h[(size_t)s * C + lane], w, acc0);
        }
        for (; j < dg; ++j) {                    // ultra-rare deg>64 tail
            int s = csr[o0 + j];
            acc0 = fmaf(h[(size_t)s * C + lane], dinv[s], acc0);
        }
        float acc = acc0 + acc1;
        float di = dinv[node];
        float hv = h[(size_t)node * C + lane];
        val = bias[lane] + di * acc + di * di * hv;
        out2[(size_t)node * C + lane] = val;
    }
    // fused centroid partial: all 4 nodes of this block belong to one graph
    red[threadIdx.x] = val;
    __syncthreads();
    if (threadIdx.x < 64) {
        int g = node_base / NPG;
        float s = red[lane] + red[64 + lane] + red[128 + lane] + red[192 + lane];
        atomicAdd(&cenacc[(size_t)g * C + lane], s);
    }
}

__global__ void cen_fin_k(const float* __restrict__ cenacc, float* __restrict__ cen,
                          float* __restrict__ cnorm) {
    int g = blockIdx.x, c = threadIdx.x;   // 64 threads
    float m = cenacc[(size_t)g * C + c] / 1000.0f;
    cen[g * C + c] = m;
    float v = m * m;
    for (int o = 32; o > 0; o >>= 1) v += __shfl_down(v, o, 64);
    if (c == 0) cnorm[g] = sqrtf(v);
}

// cosine similarity of each node row vs its graph centroid
__global__ void score_k(const float* __restrict__ out2, const float* __restrict__ cen,
                        const float* __restrict__ cnorm, float* __restrict__ score, int N) {
    int i = blockIdx.x * 256 + threadIdx.x;
    if (i < N) {
        int g = i / NPG;
        const float4* xr = (const float4*)(out2 + (size_t)i * C);
        const float4* cr = (const float4*)(cen + g * C);
        float num = 0.f, sq = 0.f;
#pragma unroll
        for (int q = 0; q < 16; ++q) {
            float4 a = xr[q], b = cr[q];
            num += a.x * b.x + a.y * b.y + a.z * b.z + a.w * b.w;
            sq  += a.x * a.x + a.y * a.y + a.z * a.z + a.w * a.w;
        }
        float den = sqrtf(sq) * cnorm[g] + 1e-8f;
        score[i] = num / den;
    }
}

// per-graph KL(softmax || uniform)
__global__ void softmax_kl_k(const float* __restrict__ score, float* __restrict__ o_kl) {
    int g = blockIdx.x, t = threadIdx.x;
    const float* s = score + (size_t)g * NPG;
    __shared__ float red[256];
    float mx = -INFINITY;
    for (int i = t; i < NPG; i += 256) mx = fmaxf(mx, s[i]);
    red[t] = mx;
    __syncthreads();
    for (int w = 128; w > 0; w >>= 1) { if (t < w) red[t] = fmaxf(red[t], red[t + w]); __syncthreads(); }
    mx = red[0];
    __syncthreads();
    float se = 0.f;
    for (int i = t; i < NPG; i += 256) se += expf(s[i] - mx);
    red[t] = se;
    __syncthreads();
    for (int w = 128; w > 0; w >>= 1) { if (t < w) red[t] += red[t + w]; __syncthreads(); }
    float lse = logf(red[0]);
    __syncthreads();
    float kl = 0.f;
    const float ln_npg = 6.9077552790f;
    for (int i = t; i < NPG; i += 256) {
        float lp = s[i] - mx - lse;
        kl += expf(lp) * (lp + ln_npg);
    }
    red[t] = kl;
    __syncthreads();
    for (int w = 128; w > 0; w >>= 1) { if (t < w) red[t] += red[t + w]; __syncthreads(); }
    if (t == 0) o_kl[g] = red[0];
}

// ---------------- per-graph full descending stable argsort (bitonic, 1024) ----------------
__global__ void sort_k(const float* __restrict__ score, int* __restrict__ sidx,
                       float* __restrict__ o_ind) {
    __shared__ unsigned long long kk[1024];
    int g = blockIdx.x, t = threadIdx.x;          // 512 threads
    for (int i = t; i < 1024; i += 512) {
        unsigned long long v;
        if (i < NPG) {
            unsigned u = __float_as_uint(score[(size_t)g * NPG + i]);
            u = (u & 0x80000000u) ? ~u : (u | 0x80000000u);
            v = ((unsigned long long)(~u) << 32) | (unsigned)i;
        } else {
            v = ~0ULL;
        }
        kk[i] = v;
    }
    __syncthreads();
    for (int k = 2; k <= 1024; k <<= 1) {
        for (int j = k >> 1; j > 0; j >>= 1) {
            for (int i = t; i < 1024; i += 512) {
                int ixj = i ^ j;
                if (ixj > i) {
                    unsigned long long a = kk[i], b = kk[ixj];
                    bool up = ((i & k) == 0);
                    if ((a > b) == up) { kk[i] = b; kk[ixj] = a; }
                }
            }
            __syncthreads();
        }
    }
    for (int i = t; i < NPG; i += 512) {
        int idx = (int)(kk[i] & 0xFFFFFFFFULL);
        sidx[(size_t)g * NPG + i] = idx;
        o_ind[(size_t)g * NPG + i] = (float)idx;
    }
}

// ---------------- top-K gather: wave-per-row, lane = channel ----------------
__global__ __launch_bounds__(256) void topk_k(const int* __restrict__ sidx,
                                              const float* __restrict__ score,
                                              const float* __restrict__ out2,
                                              int* __restrict__ mapping,
                                              float* __restrict__ o_xnew,
                                              float* __restrict__ o_batch,
                                              float* __restrict__ o_perm, int BK) {
    int w = blockIdx.x * 4 + (threadIdx.x >> 6);
    int lane = threadIdx.x & 63;
    if (w < BK) {
        int b = w / KTOP, r = w - b * KTOP;
        int node = sidx[(size_t)b * NPG + r];
        int gn = b * NPG + node;
        float tn = tanhf(score[gn]);
        float v = out2[(size_t)gn * C + lane];
        o_xnew[(size_t)w * C + lane] = v * tn;
        if (lane == 0) {
            mapping[gn] = w;
            o_perm[w] = (float)gn;
            o_batch[w] = (float)b;
        }
    }
}

// ---------------- edge re-index + mask + attr (x4 vectorized) ----------------
__global__ __launch_bounds__(256) void edge_out_k(const int* __restrict__ ei,
                                                  const float* __restrict__ eattr,
                                                  const int* __restrict__ mapping,
                                                  float* __restrict__ o_newei,
                                                  float* __restrict__ o_eattr,
                                                  float* __restrict__ o_mask, int E) {
    int q = blockIdx.x * 256 + threadIdx.x;
    int E4 = E >> 2;
    if (q < E4) {
        int4 s4 = ((const int4*)ei)[q];
        int4 d4 = ((const int4*)(ei + E))[q];
        float4 ea = ((const float4*)eattr)[q];
        int ms0 = mapping[s4.x], ms1 = mapping[s4.y], ms2 = mapping[s4.z], ms3 = mapping[s4.w];
        int md0 = mapping[d4.x], md1 = mapping[d4.y], md2 = mapping[d4.z], md3 = mapping[d4.w];
        float4 nsrc = make_float4((float)ms0, (float)ms1, (float)ms2, (float)ms3);
        float4 ndst = make_float4((float)md0, (float)md1, (float)md2, (float)md3);
        bool k0 = (ms0 >= 0) && (md0 >= 0);
        bool k1 = (ms1 >= 0) && (md1 >= 0);
        bool k2 = (ms2 >= 0) && (md2 >= 0);
        bool k3 = (ms3 >= 0) && (md3 >= 0);
        ((float4*)o_newei)[q] = nsrc;
        ((float4*)(o_newei + E))[q] = ndst;
        ((float4*)o_mask)[q] = make_float4(k0 ? 1.f : 0.f, k1 ? 1.f : 0.f,
                                           k2 ? 1.f : 0.f, k3 ? 1.f : 0.f);
        ((float4*)o_eattr)[q] = make_float4(k0 ? ea.x : 0.f, k1 ? ea.y : 0.f,
                                            k2 ? ea.z : 0.f, k3 ? ea.w : 0.f);
    }
    // scalar tail for E % 4 != 0
    int tail = E & 3;
    if (tail && q == E4) {
        for (int e = E - tail; e < E; ++e) {
            int m0 = mapping[ei[e]];
            int m1 = mapping[ei[E + e]];
            o_newei[e] = (float)m0;
            o_newei[E + e] = (float)m1;
            bool mk = (m0 >= 0) && (m1 >= 0);
            o_mask[e] = mk ? 1.0f : 0.0f;
            o_eattr[e] = mk ? eattr[e] : 0.0f;
        }
    }
}

extern "C" void kernel_launch(void* const* d_in, const int* in_sizes, int n_in,
                              void* d_out, int out_size, void* d_ws, size_t ws_size,
                              hipStream_t stream) {
    (void)n_in; (void)out_size; (void)ws_size;
    const float* x     = (const float*)d_in[1];
    const int*   ei    = (const int*)d_in[2];
    const float* eattr = (const float*)d_in[3];
    const float* W     = (const float*)d_in[5];
    const float* bias  = (const float*)d_in[6];

    const int N  = in_sizes[1] / C;    // 256000
    const int E  = in_sizes[2] / 2;    // 4096000
    const int B  = N / NPG;            // 256
    const int BK = B * KTOP;           // 128000

    // workspace layout
    char* wsp = (char*)d_ws;
    float* out2    = (float*)wsp; wsp += (size_t)N * C * 4;   // 65.5 MB
    float* dinv    = (float*)wsp; wsp += (size_t)N * 4;
    float* score   = (float*)wsp; wsp += (size_t)N * 4;
    float* cen     = (float*)wsp; wsp += (size_t)B * C * 4;
    float* cnorm   = (float*)wsp; wsp += 1024;
    int*   sidx    = (int*)wsp;   wsp += (size_t)B * NPG * 4;
    int*   mapping = (int*)wsp;   wsp += (size_t)N * 4;
    int*   deg     = (int*)wsp;   wsp += (size_t)N * 4;
    int*   off     = (int*)wsp;   wsp += (size_t)N * 4;
    float* cenacc  = (float*)wsp; wsp += (size_t)B * C * 4;

    // output layout (flat f32, reference return order)
    float* out     = (float*)d_out;
    float* o_xnew  = out;                                   // BK*C
    float* o_newei = o_xnew + (size_t)BK * C;               // 2E
    float* o_eattr = o_newei + 2 * (size_t)E;               // E
    float* o_mask  = o_eattr + (size_t)E;                   // E
    float* o_batch = o_mask + (size_t)E;                    // BK
    float* o_perm  = o_batch + (size_t)BK;                  // BK
    float* o_kl    = o_perm + (size_t)BK;                   // B
    float* o_ind   = o_kl + (size_t)B;                      // B*NPG

    // scratch aliased onto d_out (dead before those outputs are written)
    float* hbuf = out;                 // N*C floats
    int*   csr  = (int*)o_eattr;       // E ints

    hipMemsetAsync(mapping, 0xFF, (size_t)N * 4, stream);   // -1
    hipMemsetAsync(cenacc, 0, (size_t)B * C * 4, stream);

    build_graph_k<<<B, 256, 0, stream>>>(ei, E, deg, dinv, off, csr);
    gemm_k<<<(N + 511) / 512, 256, 0, stream>>>(x, W, hbuf, N);
    gather_k<<<(N + 3) / 4, 256, 0, stream>>>(csr, off, deg, hbuf, dinv, bias, out2,
                                              cenacc, N, B);
    cen_fin_k<<<B, 64, 0, stream>>>(cenacc, cen, cnorm);
    score_k<<<(N + 255) / 256, 256, 0, stream>>>(out2, cen, cnorm, score, N);
    softmax_kl_k<<<B, 256, 0, stream>>>(score, o_kl);
    sort_k<<<B, 512, 0, stream>>>(score, sidx, o_ind);
    topk_k<<<(BK + 3) / 4, 256, 0, stream>>>(sidx, score, out2, mapping,
                                             o_xnew, o_batch, o_perm, BK);
    edge_out_k<<<((E >> 2) + 256) / 256, 256, 0, stream>>>(ei, eattr, mapping,
                                                           o_newei, o_eattr, o_mask, E);
}